// Round 1
// baseline (645.230 us; speedup 1.0000x reference)
//
#include <hip/hip_runtime.h>
#include <math.h>

#define N_NODES 20000
#define N_EDGES 320000
#define DIM 64
#define SUB 16
#define NRBF 8
#define NB 5
#define LAYERS 3
#define FCIN (NRBF*SUB*NB + SUB)   // 656
#define HD 64
#define CUTOFF 5.0f
#define LOG2F_ 0.69314718055994530942f

__device__ __forceinline__ float ssp(float x) {
    // softplus(x) - log(2), numerically stable
    float sp = fmaxf(x, 0.0f) + log1pf(expf(-fabsf(x)));
    return sp - LOG2F_;
}

// xi = W_species[species]
__global__ void k_init_xi(const int* __restrict__ species,
                          const float* __restrict__ Wsp,
                          float* __restrict__ xi) {
    int i = blockIdx.x * blockDim.x + threadIdx.x;
    if (i >= N_NODES * DIM) return;
    int n = i >> 6, d = i & 63;
    xi[i] = Wsp[species[n] * DIM + d];
}

// rb[e][r] = exp(-0.5*((d[e]-mu_r)/sigma)^2), mu = linspace(0,CUTOFF,8), sigma = CUTOFF/8
__global__ void k_rb(const float* __restrict__ dist, float* __restrict__ rb) {
    int i = blockIdx.x * blockDim.x + threadIdx.x;
    if (i >= N_EDGES * NRBF) return;
    int e = i >> 3, r = i & 7;
    const float sigma = CUTOFF / NRBF;                 // 0.625
    float mu = (CUTOFF / (NRBF - 1)) * (float)r;       // step 5/7
    float t = (dist[e] - mu) / sigma;
    rb[i] = expf(-0.5f * t * t);
}

// h = xi @ W_sm[l] + b_sm[l]; si = h[:, :16], mi = h[:, 16:32]
__global__ void k_h(const float* __restrict__ xi,
                    const float* __restrict__ Wsm, const float* __restrict__ bsm,
                    float* __restrict__ si, float* __restrict__ mi, int l) {
    int i = blockIdx.x * blockDim.x + threadIdx.x;
    if (i >= N_NODES * 2 * SUB) return;
    int n = i >> 5, j = i & 31;
    const float* W = Wsm + l * DIM * 2 * SUB;
    const float* xr = xi + n * DIM;
    float v = bsm[l * 2 * SUB + j];
    #pragma unroll
    for (int d = 0; d < DIM; ++d) v = fmaf(xr[d], W[d * 2 * SUB + j], v);
    if (j < SUB) si[n * SUB + j] = v;
    else         mi[n * SUB + (j - SUB)] = v;
}

// Fused per-node: segment aggregation (register outer product) + cat + MLP + residual.
// One wave (64 lanes) per node. Lane l: s = l&15, group g = l>>4 covers
// p = g+4j (j=0..9) of the 40 (r,b) pairs; k = r*80 + s*5 + b.
__global__ __launch_bounds__(64) void k_node(
    const int* __restrict__ esrc, const int* __restrict__ edst,
    const float* __restrict__ sw, const float* __restrict__ bo,
    const float* __restrict__ rb,
    const float* __restrict__ si, const float* __restrict__ mi,
    const float* __restrict__ w0, const float* __restrict__ b0,
    const float* __restrict__ w1, const float* __restrict__ b1,
    const float* __restrict__ w2, const float* __restrict__ b2,
    float* __restrict__ xi, int l)
{
    __shared__ float cat[FCIN];
    __shared__ float h1[HD];
    __shared__ float h2[HD];

    const int n = blockIdx.x;
    const int lane = threadIdx.x;

    // edge range for node n (edge_src is sorted)
    int lo, hi;
    {
        int a = 0, b = N_EDGES;
        while (a < b) { int m = (a + b) >> 1; if (esrc[m] < n) a = m + 1; else b = m; }
        lo = a;
        b = N_EDGES;
        while (a < b) { int m = (a + b) >> 1; if (esrc[m] < n + 1) a = m + 1; else b = m; }
        hi = a;
    }

    const int s = lane & 15;
    const int g = lane >> 4;
    float acc[10];
    int rj[10], bj[10];
    #pragma unroll
    for (int j = 0; j < 10; ++j) {
        acc[j] = 0.0f;
        int p = g + 4 * j;
        rj[j] = p / 5;
        bj[j] = p - 5 * (p / 5);
    }

    for (int e = lo; e < hi; ++e) {
        int dst = edst[e];
        float swv = sw[e];
        float msv = mi[dst * SUB + s] * swv;
        const float* rbe = rb + e * NRBF;
        const float* boe = bo + e * NB;
        #pragma unroll
        for (int j = 0; j < 10; ++j)
            acc[j] = fmaf(rbe[rj[j]] * boe[bj[j]], msv, acc[j]);
    }

    #pragma unroll
    for (int j = 0; j < 10; ++j) {
        int k = rj[j] * (SUB * NB) + s * NB + bj[j];
        cat[k] = acc[j];
    }
    if (lane < SUB) cat[NRBF * SUB * NB + lane] = si[n * SUB + lane];
    __syncthreads();

    // fc0: 656 -> 64, ssp
    const float* W0 = w0 + l * FCIN * HD;
    float v = b0[l * HD + lane];
    #pragma unroll 8
    for (int k = 0; k < FCIN; ++k) v = fmaf(cat[k], W0[k * HD + lane], v);
    h1[lane] = ssp(v);
    __syncthreads();

    // fc1: 64 -> 64, ssp
    const float* W1 = w1 + l * HD * HD;
    v = b1[l * HD + lane];
    #pragma unroll
    for (int k = 0; k < HD; ++k) v = fmaf(h1[k], W1[k * HD + lane], v);
    h2[lane] = ssp(v);
    __syncthreads();

    // fc2: 64 -> 64, residual into xi
    const float* W2 = w2 + l * HD * DIM;
    v = b2[l * DIM + lane];
    #pragma unroll
    for (int k = 0; k < HD; ++k) v = fmaf(h2[k], W2[k * DIM + lane], v);
    xi[n * DIM + lane] += v;
}

extern "C" void kernel_launch(void* const* d_in, const int* in_sizes, int n_in,
                              void* d_out, int out_size, void* d_ws, size_t ws_size,
                              hipStream_t stream) {
    const int*   species = (const int*)  d_in[0];
    const int*   esrc    = (const int*)  d_in[1];
    const int*   edst    = (const int*)  d_in[2];
    const float* dist    = (const float*)d_in[3];
    const float* sw      = (const float*)d_in[4];
    const float* bo      = (const float*)d_in[5];
    const float* Wsp     = (const float*)d_in[6];
    const float* Wsm     = (const float*)d_in[7];
    const float* bsm     = (const float*)d_in[8];
    const float* w0      = (const float*)d_in[9];
    const float* b0      = (const float*)d_in[10];
    const float* w1      = (const float*)d_in[11];
    const float* b1      = (const float*)d_in[12];
    const float* w2      = (const float*)d_in[13];
    const float* b2      = (const float*)d_in[14];

    float* xi = (float*)d_out;                       // N x 64 fp32, updated in place

    // workspace layout (fp32): rb E*8 | si N*16 | mi N*16
    float* rb = (float*)d_ws;
    float* si = rb + (size_t)N_EDGES * NRBF;
    float* mi = si + (size_t)N_NODES * SUB;

    k_init_xi<<<(N_NODES * DIM + 255) / 256, 256, 0, stream>>>(species, Wsp, xi);
    k_rb<<<(N_EDGES * NRBF + 255) / 256, 256, 0, stream>>>(dist, rb);

    for (int l = 0; l < LAYERS; ++l) {
        k_h<<<(N_NODES * 2 * SUB + 255) / 256, 256, 0, stream>>>(xi, Wsm, bsm, si, mi, l);
        k_node<<<N_NODES, 64, 0, stream>>>(esrc, edst, sw, bo, rb, si, mi,
                                           w0, b0, w1, b1, w2, b2, xi, l);
    }
}

// Round 2
// 467.619 us; speedup vs baseline: 1.3798x; 1.3798x over previous
//
#include <hip/hip_runtime.h>
#include <math.h>

#define N_NODES 20000
#define N_EDGES 320000
#define DIM 64
#define SUB 16
#define NRBF 8
#define NB 5
#define LAYERS 3
#define FCIN (NRBF*SUB*NB + SUB)   // 656
#define HD 64
#define CUTOFF 5.0f
#define LOG2F_ 0.69314718055994530942f

__device__ __forceinline__ float ssp(float x) {
    float sp = fmaxf(x, 0.0f) + log1pf(expf(-fabsf(x)));
    return sp - LOG2F_;
}

// --- one-time kernels -------------------------------------------------------

// rowptr[n] = lower_bound(esrc, n), n in [0, N]; esrc sorted
__global__ void k_rowptr(const int* __restrict__ esrc, int* __restrict__ rowptr) {
    int n = blockIdx.x * blockDim.x + threadIdx.x;
    if (n > N_NODES) return;
    int a = 0, b = N_EDGES;
    while (a < b) { int m = (a + b) >> 1; if (esrc[m] < n) a = m + 1; else b = m; }
    rowptr[n] = a;
}

// u[e][g*10+j] = sw[e] * rb[e][r] * bo[e][b], where p=g+4j, r=p/5, b=p%5.
// Layer-independent; folds the radial basis, switch, and bond order.
__global__ void k_u(const float* __restrict__ dist, const float* __restrict__ sw,
                    const float* __restrict__ bo, float* __restrict__ u) {
    int i = blockIdx.x * blockDim.x + threadIdx.x;
    if (i >= N_EDGES * 40) return;
    int e = i / 40, t = i - e * 40;
    int g = t / 10, j = t - g * 10;
    int p = g + 4 * j;
    int r = p / 5, b = p - r * 5;
    float mu = (CUTOFF / (NRBF - 1)) * (float)r;
    float inv_sigma = (float)NRBF / CUTOFF;
    float z = (dist[e] - mu) * inv_sigma;
    u[i] = sw[e] * expf(-0.5f * z * z) * bo[e * NB + b];
}

// Pre-permute W0 rows into the k' (cat') ordering so k_mlp streams rows 0..655.
// orig(k') for k'<640: j=k'>>6, l=k'&63, g=l>>4, s=l&15, p=g+4j, orig=(p/5)*80+s*5+p%5
__global__ void k_permw(const float* __restrict__ w0, float* __restrict__ w0p) {
    int i = blockIdx.x * blockDim.x + threadIdx.x;
    if (i >= LAYERS * FCIN * HD) return;
    int c = i & 63;
    int kp = (i >> 6) % FCIN;
    int l = i / (FCIN * HD);
    int orig;
    if (kp < 640) {
        int j = kp >> 6, lx = kp & 63, g = lx >> 4, s = lx & 15;
        int p = g + 4 * j;
        orig = (p / 5) * 80 + s * 5 + (p - 5 * (p / 5));
    } else orig = kp;
    w0p[i] = w0[(size_t)l * FCIN * HD + orig * HD + c];
}

// xi = W_species[species]
__global__ void k_init_xi(const int* __restrict__ species,
                          const float* __restrict__ Wsp,
                          float* __restrict__ xi) {
    int i = blockIdx.x * blockDim.x + threadIdx.x;
    if (i >= N_NODES * DIM) return;
    int n = i >> 6, d = i & 63;
    xi[i] = Wsp[species[n] * DIM + d];
}

// --- per-layer kernels ------------------------------------------------------

// h = xi @ W_sm[l] + b_sm[l]; si = h[:,:16], mi = h[:,16:32]
__global__ void k_h(const float* __restrict__ xi,
                    const float* __restrict__ Wsm, const float* __restrict__ bsm,
                    float* __restrict__ si, float* __restrict__ mi, int l) {
    int i = blockIdx.x * blockDim.x + threadIdx.x;
    if (i >= N_NODES * 2 * SUB) return;
    int n = i >> 5, j = i & 31;
    const float* W = Wsm + l * DIM * 2 * SUB;
    const float* xr = xi + n * DIM;
    float v = bsm[l * 2 * SUB + j];
    #pragma unroll
    for (int d = 0; d < DIM; ++d) v = fmaf(xr[d], W[d * 2 * SUB + j], v);
    if (j < SUB) si[n * SUB + j] = v;
    else         mi[n * SUB + (j - SUB)] = v;
}

// Aggregation: one wave per node. Lane (g=lane>>4, s=lane&15) accumulates
// acc[j] = sum_e u[e][g*10+j] * mi[dst_e][s].  Writes cat' (permuted layout):
// cat'[n][j*64 + lane] = acc[j]; cat'[n][640+s] = si[n][s].
__global__ __launch_bounds__(256) void k_agg(
    const int* __restrict__ rowptr, const int* __restrict__ edst,
    const float* __restrict__ u,
    const float* __restrict__ si, const float* __restrict__ mi,
    float* __restrict__ cat)
{
    const int lane = threadIdx.x & 63;
    const int n = blockIdx.x * 4 + (threadIdx.x >> 6);
    const int s = lane & 15;
    const int g = lane >> 4;
    const int lo = rowptr[n], hi = rowptr[n + 1];

    float a0=0,a1=0,a2=0,a3=0,a4=0,a5=0,a6=0,a7=0,a8=0,a9=0;
    for (int e = lo; e < hi; ++e) {
        float m = mi[edst[e] * SUB + s];
        const float* up = u + (size_t)e * 40 + g * 10;
        float2 u0 = *(const float2*)(up);
        float2 u1 = *(const float2*)(up + 2);
        float2 u2 = *(const float2*)(up + 4);
        float2 u3 = *(const float2*)(up + 6);
        float2 u4 = *(const float2*)(up + 8);
        a0 = fmaf(u0.x, m, a0); a1 = fmaf(u0.y, m, a1);
        a2 = fmaf(u1.x, m, a2); a3 = fmaf(u1.y, m, a3);
        a4 = fmaf(u2.x, m, a4); a5 = fmaf(u2.y, m, a5);
        a6 = fmaf(u3.x, m, a6); a7 = fmaf(u3.y, m, a7);
        a8 = fmaf(u4.x, m, a8); a9 = fmaf(u4.y, m, a9);
    }
    float* cp = cat + (size_t)n * FCIN;
    cp[0*64+lane]=a0; cp[1*64+lane]=a1; cp[2*64+lane]=a2; cp[3*64+lane]=a3;
    cp[4*64+lane]=a4; cp[5*64+lane]=a5; cp[6*64+lane]=a6; cp[7*64+lane]=a7;
    cp[8*64+lane]=a8; cp[9*64+lane]=a9;
    if (lane < SUB) cp[640 + lane] = si[n * SUB + lane];
}

// Fused MLP: each wave owns 8 nodes. fc0 uses scalar (SGPR) cat loads +
// vector W0p row loads (8x reuse, 8 independent FMA chains). fc1/fc2 via
// per-wave LDS transpose. No inter-wave communication -> no barriers.
__global__ __launch_bounds__(256) void k_mlp(
    const float* __restrict__ cat, const float* __restrict__ w0p,
    const float* __restrict__ b0,
    const float* __restrict__ w1, const float* __restrict__ b1,
    const float* __restrict__ w2, const float* __restrict__ b2,
    float* __restrict__ xi, int l)
{
    __shared__ float h1s[32][64];
    __shared__ float h2s[32][64];
    const int lane = threadIdx.x & 63;
    const int wid  = threadIdx.x >> 6;
    const int n0 = __builtin_amdgcn_readfirstlane(blockIdx.x * 32 + wid * 8);

    const float* W0 = w0p + (size_t)l * FCIN * HD;
    const float* c0 = cat + (size_t)n0 * FCIN;

    float acc0,acc1,acc2,acc3,acc4,acc5,acc6,acc7;
    {
        float bv = b0[l * HD + lane];
        acc0=bv; acc1=bv; acc2=bv; acc3=bv; acc4=bv; acc5=bv; acc6=bv; acc7=bv;
    }
    #pragma unroll 8
    for (int k = 0; k < FCIN; ++k) {
        float w = W0[k * HD + lane];
        acc0 = fmaf(c0[0*FCIN + k], w, acc0);
        acc1 = fmaf(c0[1*FCIN + k], w, acc1);
        acc2 = fmaf(c0[2*FCIN + k], w, acc2);
        acc3 = fmaf(c0[3*FCIN + k], w, acc3);
        acc4 = fmaf(c0[4*FCIN + k], w, acc4);
        acc5 = fmaf(c0[5*FCIN + k], w, acc5);
        acc6 = fmaf(c0[6*FCIN + k], w, acc6);
        acc7 = fmaf(c0[7*FCIN + k], w, acc7);
    }
    const int r0 = wid * 8;
    h1s[r0+0][lane]=ssp(acc0); h1s[r0+1][lane]=ssp(acc1);
    h1s[r0+2][lane]=ssp(acc2); h1s[r0+3][lane]=ssp(acc3);
    h1s[r0+4][lane]=ssp(acc4); h1s[r0+5][lane]=ssp(acc5);
    h1s[r0+6][lane]=ssp(acc6); h1s[r0+7][lane]=ssp(acc7);

    // fc1: 64 -> 64
    const float* W1 = w1 + (size_t)l * HD * HD;
    {
        float bv = b1[l * HD + lane];
        acc0=bv; acc1=bv; acc2=bv; acc3=bv; acc4=bv; acc5=bv; acc6=bv; acc7=bv;
    }
    #pragma unroll 8
    for (int k = 0; k < HD; ++k) {
        float w = W1[k * HD + lane];
        acc0 = fmaf(h1s[r0+0][k], w, acc0);
        acc1 = fmaf(h1s[r0+1][k], w, acc1);
        acc2 = fmaf(h1s[r0+2][k], w, acc2);
        acc3 = fmaf(h1s[r0+3][k], w, acc3);
        acc4 = fmaf(h1s[r0+4][k], w, acc4);
        acc5 = fmaf(h1s[r0+5][k], w, acc5);
        acc6 = fmaf(h1s[r0+6][k], w, acc6);
        acc7 = fmaf(h1s[r0+7][k], w, acc7);
    }
    h2s[r0+0][lane]=ssp(acc0); h2s[r0+1][lane]=ssp(acc1);
    h2s[r0+2][lane]=ssp(acc2); h2s[r0+3][lane]=ssp(acc3);
    h2s[r0+4][lane]=ssp(acc4); h2s[r0+5][lane]=ssp(acc5);
    h2s[r0+6][lane]=ssp(acc6); h2s[r0+7][lane]=ssp(acc7);

    // fc2: 64 -> 64 + residual
    const float* W2 = w2 + (size_t)l * HD * DIM;
    {
        float bv = b2[l * DIM + lane];
        acc0=bv; acc1=bv; acc2=bv; acc3=bv; acc4=bv; acc5=bv; acc6=bv; acc7=bv;
    }
    #pragma unroll 8
    for (int k = 0; k < HD; ++k) {
        float w = W2[k * DIM + lane];
        acc0 = fmaf(h2s[r0+0][k], w, acc0);
        acc1 = fmaf(h2s[r0+1][k], w, acc1);
        acc2 = fmaf(h2s[r0+2][k], w, acc2);
        acc3 = fmaf(h2s[r0+3][k], w, acc3);
        acc4 = fmaf(h2s[r0+4][k], w, acc4);
        acc5 = fmaf(h2s[r0+5][k], w, acc5);
        acc6 = fmaf(h2s[r0+6][k], w, acc6);
        acc7 = fmaf(h2s[r0+7][k], w, acc7);
    }
    xi[(size_t)(n0+0)*DIM + lane] += acc0;
    xi[(size_t)(n0+1)*DIM + lane] += acc1;
    xi[(size_t)(n0+2)*DIM + lane] += acc2;
    xi[(size_t)(n0+3)*DIM + lane] += acc3;
    xi[(size_t)(n0+4)*DIM + lane] += acc4;
    xi[(size_t)(n0+5)*DIM + lane] += acc5;
    xi[(size_t)(n0+6)*DIM + lane] += acc6;
    xi[(size_t)(n0+7)*DIM + lane] += acc7;
}

extern "C" void kernel_launch(void* const* d_in, const int* in_sizes, int n_in,
                              void* d_out, int out_size, void* d_ws, size_t ws_size,
                              hipStream_t stream) {
    const int*   species = (const int*)  d_in[0];
    const int*   esrc    = (const int*)  d_in[1];
    const int*   edst    = (const int*)  d_in[2];
    const float* dist    = (const float*)d_in[3];
    const float* sw      = (const float*)d_in[4];
    const float* bo      = (const float*)d_in[5];
    const float* Wsp     = (const float*)d_in[6];
    const float* Wsm     = (const float*)d_in[7];
    const float* bsm     = (const float*)d_in[8];
    const float* w0      = (const float*)d_in[9];
    const float* b0      = (const float*)d_in[10];
    const float* w1      = (const float*)d_in[11];
    const float* b1      = (const float*)d_in[12];
    const float* w2      = (const float*)d_in[13];
    const float* b2      = (const float*)d_in[14];

    float* xi = (float*)d_out;   // N x 64 fp32, updated in place

    // ws layout (floats): u E*40 | cat N*656 | si N*16 | mi N*16 | w0p 3*656*64 | rowptr
    float* u    = (float*)d_ws;
    float* cat  = u    + (size_t)N_EDGES * 40;
    float* si   = cat  + (size_t)N_NODES * FCIN;
    float* mi   = si   + (size_t)N_NODES * SUB;
    float* w0p  = mi   + (size_t)N_NODES * SUB;
    int*   rowptr = (int*)(w0p + (size_t)LAYERS * FCIN * HD);

    k_rowptr<<<(N_NODES + 1 + 255) / 256, 256, 0, stream>>>(esrc, rowptr);
    k_u<<<(N_EDGES * 40 + 255) / 256, 256, 0, stream>>>(dist, sw, bo, u);
    k_permw<<<(LAYERS * FCIN * HD + 255) / 256, 256, 0, stream>>>(w0, w0p);
    k_init_xi<<<(N_NODES * DIM + 255) / 256, 256, 0, stream>>>(species, Wsp, xi);

    for (int l = 0; l < LAYERS; ++l) {
        k_h<<<(N_NODES * 2 * SUB + 255) / 256, 256, 0, stream>>>(xi, Wsm, bsm, si, mi, l);
        k_agg<<<N_NODES / 4, 256, 0, stream>>>(rowptr, edst, u, si, mi, cat);
        k_mlp<<<N_NODES / 32, 256, 0, stream>>>(cat, w0p, b0, w1, b1, w2, b2, xi, l);
    }
}

// Round 3
// 245.101 us; speedup vs baseline: 2.6325x; 1.9079x over previous
//
#include <hip/hip_runtime.h>
#include <math.h>

#define N_NODES 20000
#define N_EDGES 320000
#define DIM 64
#define SUB 16
#define NRBF 8
#define NB 5
#define LAYERS 3
#define FCIN (NRBF*SUB*NB + SUB)   // 656
#define KPAD 672                   // 21 * 32
#define NKK 21
#define HD 64
#define CUTOFF 5.0f
#define LOG2F_ 0.69314718055994530942f

typedef __attribute__((ext_vector_type(8))) short short8;
typedef __attribute__((ext_vector_type(4))) float float4v;
typedef __attribute__((ext_vector_type(4))) unsigned short ushort4v;

__device__ __forceinline__ float ssp(float x) {
    float sp = fmaxf(x, 0.0f) + log1pf(expf(-fabsf(x)));
    return sp - LOG2F_;
}

__device__ __forceinline__ unsigned short f2bf(float x) {
    unsigned int u = __float_as_uint(x);
    unsigned int r = (u + 0x7FFFu + ((u >> 16) & 1u)) >> 16;
    return (unsigned short)r;
}
__device__ __forceinline__ float bf2f(unsigned short s) {
    unsigned int u = ((unsigned int)s) << 16;
    return __uint_as_float(u);
}

// --- one-time kernels -------------------------------------------------------

__global__ void k_rowptr(const int* __restrict__ esrc, int* __restrict__ rowptr) {
    int n = blockIdx.x * blockDim.x + threadIdx.x;
    if (n > N_NODES) return;
    int a = 0, b = N_EDGES;
    while (a < b) { int m = (a + b) >> 1; if (esrc[m] < n) a = m + 1; else b = m; }
    rowptr[n] = a;
}

// u16[e][g*12+j] = bf16( sw[e] * rb[r] * bo[b] ), p=g+4j, r=p/5, b=p%5; j=10,11 pad=0
__global__ void k_u(const float* __restrict__ dist, const float* __restrict__ sw,
                    const float* __restrict__ bo, unsigned short* __restrict__ u16) {
    int i = blockIdx.x * blockDim.x + threadIdx.x;
    if (i >= N_EDGES * 48) return;
    int e = i / 48, t = i - e * 48;
    int g = t / 12, j = t - g * 12;
    float v = 0.0f;
    if (j < 10) {
        int p = g + 4 * j;
        int r = p / 5, b = p - r * 5;
        float mu = (CUTOFF / (NRBF - 1)) * (float)r;
        float inv_sigma = (float)NRBF / CUTOFF;
        float z = (dist[e] - mu) * inv_sigma;
        v = sw[e] * expf(-0.5f * z * z) * bo[e * NB + b];
    }
    u16[i] = f2bf(v);
}

// Pack weights into MFMA B-fragment order (bf16).
// w0f: [L][21 kk][4 nf][64 lane][8 j]; cat' row index kp = kk*32+(lane>>4)*8+j maps to
// original k: kp<640: j10=kp>>6, rem=kp&63, g=rem>>4, s=rem&15, p=g+4*j10,
//             orig=(p/5)*80+s*5+p%5 ; 640<=kp<656: orig=kp (si block); kp>=656: 0.
// w1f/w2f: [L][2 kk][4 nf][64 lane][8 j], orig = kp directly.
__global__ void k_packw(const float* __restrict__ w0, const float* __restrict__ w1,
                        const float* __restrict__ w2,
                        short* __restrict__ w0f, short* __restrict__ w1f,
                        short* __restrict__ w2f) {
    int i = blockIdx.x * blockDim.x + threadIdx.x;
    const int SZ0 = LAYERS * NKK * 4 * 64 * 8;       // 129024
    const int SZ12 = LAYERS * 2 * 4 * 64 * 8;        // 12288
    if (i < SZ0) {
        int j = i & 7, t = i >> 3;
        int lane = t & 63; t >>= 6;
        int nf = t & 3; t >>= 2;
        int kk = t % NKK, l = t / NKK;
        int kp = kk * 32 + (lane >> 4) * 8 + j;
        int col = nf * 16 + (lane & 15);
        float v = 0.0f;
        if (kp < FCIN) {
            int orig;
            if (kp < 640) {
                int j10 = kp >> 6, rem = kp & 63, g = rem >> 4, s = rem & 15;
                int p = g + 4 * j10;
                orig = (p / 5) * 80 + s * 5 + (p - 5 * (p / 5));
            } else orig = kp;
            v = w0[((size_t)l * FCIN + orig) * HD + col];
        }
        w0f[i] = (short)f2bf(v);
        return;
    }
    i -= SZ0;
    if (i < 2 * SZ12) {
        const float* W = (i < SZ12) ? w1 : w2;
        short* Wf = (i < SZ12) ? w1f : w2f;
        int ii = (i < SZ12) ? i : i - SZ12;
        int j = ii & 7, t = ii >> 3;
        int lane = t & 63; t >>= 6;
        int nf = t & 3; t >>= 2;
        int kk = t & 1, l = t >> 1;
        int kp = kk * 32 + (lane >> 4) * 8 + j;
        int col = nf * 16 + (lane & 15);
        Wf[ii] = (short)f2bf(W[((size_t)l * HD + kp) * HD + col]);
    }
}

__global__ void k_init_xi(const int* __restrict__ species,
                          const float* __restrict__ Wsp,
                          float* __restrict__ xi) {
    int i = blockIdx.x * blockDim.x + threadIdx.x;
    if (i >= N_NODES * DIM) return;
    int n = i >> 6, d = i & 63;
    xi[i] = Wsp[species[n] * DIM + d];
}

// --- per-layer kernels ------------------------------------------------------

__global__ void k_h(const float* __restrict__ xi,
                    const float* __restrict__ Wsm, const float* __restrict__ bsm,
                    float* __restrict__ si, float* __restrict__ mi, int l) {
    int i = blockIdx.x * blockDim.x + threadIdx.x;
    if (i >= N_NODES * 2 * SUB) return;
    int n = i >> 5, j = i & 31;
    const float* W = Wsm + l * DIM * 2 * SUB;
    const float* xr = xi + n * DIM;
    float v = bsm[l * 2 * SUB + j];
    #pragma unroll
    for (int d = 0; d < DIM; ++d) v = fmaf(xr[d], W[d * 2 * SUB + j], v);
    if (j < SUB) si[n * SUB + j] = v;
    else         mi[n * SUB + (j - SUB)] = v;
}

// Aggregation: one wave per node; lane (g=lane>>4, s=lane&15).
// acc[j] = sum_e u[e][g*12+j] * mi[dst_e][s]; store bf16 cat':
// cat'[n][j*64+lane] = acc[j]; cat'[n][640+s] = si; cols 656..671 = 0.
__global__ __launch_bounds__(256) void k_agg(
    const int* __restrict__ rowptr, const int* __restrict__ edst,
    const unsigned short* __restrict__ u16,
    const float* __restrict__ si, const float* __restrict__ mi,
    unsigned short* __restrict__ cat)
{
    const int lane = threadIdx.x & 63;
    const int n = blockIdx.x * 4 + (threadIdx.x >> 6);
    const int s = lane & 15;
    const int g = lane >> 4;
    const int lo = rowptr[n], hi = rowptr[n + 1];

    float a0=0,a1=0,a2=0,a3=0,a4=0,a5=0,a6=0,a7=0,a8=0,a9=0;
    for (int e = lo; e < hi; ++e) {
        float m = mi[edst[e] * SUB + s];
        const unsigned short* up = u16 + (size_t)e * 48 + g * 12;
        ushort4v ua = *(const ushort4v*)(up);
        ushort4v ub = *(const ushort4v*)(up + 4);
        unsigned int uc = *(const unsigned int*)(up + 8);
        a0 = fmaf(bf2f(ua.x), m, a0); a1 = fmaf(bf2f(ua.y), m, a1);
        a2 = fmaf(bf2f(ua.z), m, a2); a3 = fmaf(bf2f(ua.w), m, a3);
        a4 = fmaf(bf2f(ub.x), m, a4); a5 = fmaf(bf2f(ub.y), m, a5);
        a6 = fmaf(bf2f(ub.z), m, a6); a7 = fmaf(bf2f(ub.w), m, a7);
        a8 = fmaf(bf2f((unsigned short)(uc & 0xFFFFu)), m, a8);
        a9 = fmaf(bf2f((unsigned short)(uc >> 16)), m, a9);
    }
    unsigned short* cp = cat + (size_t)n * KPAD;
    cp[0*64+lane]=f2bf(a0); cp[1*64+lane]=f2bf(a1); cp[2*64+lane]=f2bf(a2);
    cp[3*64+lane]=f2bf(a3); cp[4*64+lane]=f2bf(a4); cp[5*64+lane]=f2bf(a5);
    cp[6*64+lane]=f2bf(a6); cp[7*64+lane]=f2bf(a7); cp[8*64+lane]=f2bf(a8);
    cp[9*64+lane]=f2bf(a9);
    if (lane < SUB)      cp[640 + lane] = f2bf(si[n * SUB + lane]);
    else if (lane < 32)  cp[640 + lane] = 0;   // pad cols 656..671
}

// Fused MFMA MLP: 16 nodes/block, 4 waves; wave w owns output cols [16w,16w+16),
// full K. fc0: K=672 (21 steps), A from cat (bf16, global, L1-shared across waves),
// B from pre-packed fragments. fc1/fc2 via LDS (stride 72 to dodge bank conflicts).
__global__ __launch_bounds__(256) void k_mlp(
    const unsigned short* __restrict__ cat,
    const short* __restrict__ w0f, const float* __restrict__ b0,
    const short* __restrict__ w1f, const float* __restrict__ b1,
    const short* __restrict__ w2f, const float* __restrict__ b2,
    float* __restrict__ xi, int l)
{
    __shared__ __align__(16) unsigned short h1[16][72];
    __shared__ __align__(16) unsigned short h2[16][72];
    const int lane = threadIdx.x & 63;
    const int w = threadIdx.x >> 6;
    const int n0 = blockIdx.x * 16;
    const int r = lane & 15, g = lane >> 4;

    // fc0
    const short* Ap = (const short*)cat + (size_t)(n0 + r) * KPAD + g * 8;
    const short* Bp = w0f + ((size_t)l * NKK * 256 + w * 64 + lane) * 8;
    float bv = b0[l * HD + w * 16 + r];
    float4v acc = {bv, bv, bv, bv};
    #pragma unroll 7
    for (int kk = 0; kk < NKK; ++kk) {
        short8 a = *(const short8*)(Ap + kk * 32);
        short8 b = *(const short8*)(Bp + (size_t)kk * 2048);
        acc = __builtin_amdgcn_mfma_f32_16x16x32_bf16(a, b, acc, 0, 0, 0);
    }
    #pragma unroll
    for (int i = 0; i < 4; ++i)
        h1[g * 4 + i][w * 16 + r] = f2bf(ssp(acc[i]));
    __syncthreads();

    // fc1
    bv = b1[l * HD + w * 16 + r];
    float4v acc1 = {bv, bv, bv, bv};
    #pragma unroll
    for (int kk = 0; kk < 2; ++kk) {
        short8 a = *(const short8*)((const short*)&h1[r][kk * 32 + g * 8]);
        short8 b = *(const short8*)(w1f + ((size_t)(l * 2 + kk) * 256 + w * 64 + lane) * 8);
        acc1 = __builtin_amdgcn_mfma_f32_16x16x32_bf16(a, b, acc1, 0, 0, 0);
    }
    #pragma unroll
    for (int i = 0; i < 4; ++i)
        h2[g * 4 + i][w * 16 + r] = f2bf(ssp(acc1[i]));
    __syncthreads();

    // fc2 + residual
    bv = b2[l * DIM + w * 16 + r];
    float4v acc2 = {bv, bv, bv, bv};
    #pragma unroll
    for (int kk = 0; kk < 2; ++kk) {
        short8 a = *(const short8*)((const short*)&h2[r][kk * 32 + g * 8]);
        short8 b = *(const short8*)(w2f + ((size_t)(l * 2 + kk) * 256 + w * 64 + lane) * 8);
        acc2 = __builtin_amdgcn_mfma_f32_16x16x32_bf16(a, b, acc2, 0, 0, 0);
    }
    #pragma unroll
    for (int i = 0; i < 4; ++i)
        xi[(size_t)(n0 + g * 4 + i) * DIM + w * 16 + r] += acc2[i];
}

extern "C" void kernel_launch(void* const* d_in, const int* in_sizes, int n_in,
                              void* d_out, int out_size, void* d_ws, size_t ws_size,
                              hipStream_t stream) {
    const int*   species = (const int*)  d_in[0];
    const int*   esrc    = (const int*)  d_in[1];
    const int*   edst    = (const int*)  d_in[2];
    const float* dist    = (const float*)d_in[3];
    const float* sw      = (const float*)d_in[4];
    const float* bo      = (const float*)d_in[5];
    const float* Wsp     = (const float*)d_in[6];
    const float* Wsm     = (const float*)d_in[7];
    const float* bsm     = (const float*)d_in[8];
    const float* w0      = (const float*)d_in[9];
    const float* b0      = (const float*)d_in[10];
    const float* w1      = (const float*)d_in[11];
    const float* b1      = (const float*)d_in[12];
    const float* w2      = (const float*)d_in[13];
    const float* b2      = (const float*)d_in[14];

    float* xi = (float*)d_out;   // N x 64 fp32, updated in place

    // ws layout: u16 E*48 ush | si N*16 f | mi N*16 f | cat N*672 ush |
    //            w0f 129024 sh | w1f 12288 sh | w2f 12288 sh | rowptr (N+1) int
    unsigned short* u16 = (unsigned short*)d_ws;
    float* si  = (float*)(u16 + (size_t)N_EDGES * 48);
    float* mi  = si + (size_t)N_NODES * SUB;
    unsigned short* cat = (unsigned short*)(mi + (size_t)N_NODES * SUB);
    short* w0f = (short*)(cat + (size_t)N_NODES * KPAD);
    short* w1f = w0f + (size_t)LAYERS * NKK * 2048;
    short* w2f = w1f + (size_t)LAYERS * 2 * 2048;
    int* rowptr = (int*)(w2f + (size_t)LAYERS * 2 * 2048);

    k_rowptr<<<(N_NODES + 1 + 255) / 256, 256, 0, stream>>>(esrc, rowptr);
    k_u<<<(N_EDGES * 48 + 255) / 256, 256, 0, stream>>>(dist, sw, bo, u16);
    {
        int total = LAYERS * NKK * 2048 + 2 * LAYERS * 2 * 2048;
        k_packw<<<(total + 255) / 256, 256, 0, stream>>>(w0, w1, w2, w0f, w1f, w2f);
    }
    k_init_xi<<<(N_NODES * DIM + 255) / 256, 256, 0, stream>>>(species, Wsp, xi);

    for (int l = 0; l < LAYERS; ++l) {
        k_h<<<(N_NODES * 2 * SUB + 255) / 256, 256, 0, stream>>>(xi, Wsm, bsm, si, mi, l);
        k_agg<<<N_NODES / 4, 256, 0, stream>>>(rowptr, edst, u16, si, mi, cat);
        k_mlp<<<N_NODES / 16, 256, 0, stream>>>(cat, w0f, b0, w1f, b1, w2f, b2, xi, l);
    }
}

// Round 4
// 212.665 us; speedup vs baseline: 3.0340x; 1.1525x over previous
//
#include <hip/hip_runtime.h>
#include <math.h>

#define N_NODES 20000
#define N_EDGES 320000
#define DIM 64
#define SUB 16
#define NRBF 8
#define NB 5
#define LAYERS 3
#define FCIN (NRBF*SUB*NB + SUB)   // 656
#define KPAD 672                   // 21 * 32
#define NKK 21
#define HD 64
#define CUTOFF 5.0f
#define LOG2F_ 0.69314718055994530942f

typedef __attribute__((ext_vector_type(8))) short short8;
typedef __attribute__((ext_vector_type(4))) float float4v;
typedef __attribute__((ext_vector_type(4))) unsigned short ushort4v;
typedef __attribute__((ext_vector_type(2))) unsigned int uint2v;

__device__ __forceinline__ float ssp(float x) {
    float sp = fmaxf(x, 0.0f) + log1pf(expf(-fabsf(x)));
    return sp - LOG2F_;
}

__device__ __forceinline__ unsigned short f2bf(float x) {
    unsigned int u = __float_as_uint(x);
    unsigned int r = (u + 0x7FFFu + ((u >> 16) & 1u)) >> 16;
    return (unsigned short)r;
}
__device__ __forceinline__ float bf2f(unsigned short s) {
    unsigned int u = ((unsigned int)s) << 16;
    return __uint_as_float(u);
}

// --- one-time kernels -------------------------------------------------------

__global__ void k_rowptr(const int* __restrict__ esrc, int* __restrict__ rowptr) {
    int n = blockIdx.x * blockDim.x + threadIdx.x;
    if (n > N_NODES) return;
    int a = 0, b = N_EDGES;
    while (a < b) { int m = (a + b) >> 1; if (esrc[m] < n) a = m + 1; else b = m; }
    rowptr[n] = a;
}

// u16[e][g*12+j] = bf16( sw[e] * rb[r] * bo[b] ), p=g+4j, r=p/5, b=p%5; j=10,11 pad=0
__global__ void k_u(const float* __restrict__ dist, const float* __restrict__ sw,
                    const float* __restrict__ bo, unsigned short* __restrict__ u16) {
    int i = blockIdx.x * blockDim.x + threadIdx.x;
    if (i >= N_EDGES * 48) return;
    int e = i / 48, t = i - e * 48;
    int g = t / 12, j = t - g * 12;
    float v = 0.0f;
    if (j < 10) {
        int p = g + 4 * j;
        int r = p / 5, b = p - r * 5;
        float mu = (CUTOFF / (NRBF - 1)) * (float)r;
        float inv_sigma = (float)NRBF / CUTOFF;
        float z = (dist[e] - mu) * inv_sigma;
        v = sw[e] * expf(-0.5f * z * z) * bo[e * NB + b];
    }
    u16[i] = f2bf(v);
}

// Pack weights into MFMA B-fragment order (bf16). Same layout as round 3.
__global__ void k_packw(const float* __restrict__ w0, const float* __restrict__ w1,
                        const float* __restrict__ w2,
                        short* __restrict__ w0f, short* __restrict__ w1f,
                        short* __restrict__ w2f) {
    int i = blockIdx.x * blockDim.x + threadIdx.x;
    const int SZ0 = LAYERS * NKK * 4 * 64 * 8;       // 129024
    const int SZ12 = LAYERS * 2 * 4 * 64 * 8;        // 12288
    if (i < SZ0) {
        int j = i & 7, t = i >> 3;
        int lane = t & 63; t >>= 6;
        int nf = t & 3; t >>= 2;
        int kk = t % NKK, l = t / NKK;
        int kp = kk * 32 + (lane >> 4) * 8 + j;
        int col = nf * 16 + (lane & 15);
        float v = 0.0f;
        if (kp < FCIN) {
            int orig;
            if (kp < 640) {
                int j10 = kp >> 6, rem = kp & 63, g = rem >> 4, s = rem & 15;
                int p = g + 4 * j10;
                orig = (p / 5) * 80 + s * 5 + (p - 5 * (p / 5));
            } else orig = kp;
            v = w0[((size_t)l * FCIN + orig) * HD + col];
        }
        w0f[i] = (short)f2bf(v);
        return;
    }
    i -= SZ0;
    if (i < 2 * SZ12) {
        const float* W = (i < SZ12) ? w1 : w2;
        short* Wf = (i < SZ12) ? w1f : w2f;
        int ii = (i < SZ12) ? i : i - SZ12;
        int j = ii & 7, t = ii >> 3;
        int lane = t & 63; t >>= 6;
        int nf = t & 3; t >>= 2;
        int kk = t & 1, l = t >> 1;
        int kp = kk * 32 + (lane >> 4) * 8 + j;
        int col = nf * 16 + (lane & 15);
        Wf[ii] = (short)f2bf(W[((size_t)l * HD + kp) * HD + col]);
    }
}

__global__ void k_init_xi(const int* __restrict__ species,
                          const float* __restrict__ Wsp,
                          float* __restrict__ xi) {
    int i = blockIdx.x * blockDim.x + threadIdx.x;
    if (i >= N_NODES * DIM) return;
    int n = i >> 6, d = i & 63;
    xi[i] = Wsp[species[n] * DIM + d];
}

// --- per-layer kernels ------------------------------------------------------

// h = xi @ W_sm[l] + b_sm[l]; si fp32, mi bf16 (feeds the edge gather)
__global__ void k_h(const float* __restrict__ xi,
                    const float* __restrict__ Wsm, const float* __restrict__ bsm,
                    float* __restrict__ si, unsigned short* __restrict__ mi16, int l) {
    int i = blockIdx.x * blockDim.x + threadIdx.x;
    if (i >= N_NODES * 2 * SUB) return;
    int n = i >> 5, j = i & 31;
    const float* W = Wsm + l * DIM * 2 * SUB;
    const float* xr = xi + n * DIM;
    float v = bsm[l * 2 * SUB + j];
    #pragma unroll
    for (int d = 0; d < DIM; ++d) v = fmaf(xr[d], W[d * 2 * SUB + j], v);
    if (j < SUB) si[n * SUB + j] = v;
    else         mi16[n * SUB + (j - SUB)] = f2bf(v);
}

// Edge-parallel gather: medge[e][0:16] = mi16[edst[e]][0:16]. uint2 = 4 bf16/lane.
__global__ void k_gather(const int* __restrict__ edst,
                         const unsigned short* __restrict__ mi16,
                         unsigned short* __restrict__ medge) {
    int i = blockIdx.x * blockDim.x + threadIdx.x;   // i < E*4
    if (i >= N_EDGES * 4) return;
    int e = i >> 2, q = i & 3;
    int dst = edst[e];
    ((uint2v*)medge)[i] = ((const uint2v*)mi16)[dst * 4 + q];
}

// Aggregation: one wave per node; lane (g=lane>>4, s=lane&15).
// acc[j] = sum_e u16[e][g*12+j] * medge[e][s]; all addresses affine in e ->
// compiler pipelines loads. Store bf16 cat' (permuted layout).
__global__ __launch_bounds__(256) void k_agg(
    const int* __restrict__ rowptr,
    const unsigned short* __restrict__ u16,
    const unsigned short* __restrict__ medge,
    const float* __restrict__ si,
    unsigned short* __restrict__ cat)
{
    const int lane = threadIdx.x & 63;
    const int n = blockIdx.x * 4 + (threadIdx.x >> 6);
    const int s = lane & 15;
    const int g = lane >> 4;
    const int lo = rowptr[n], hi = rowptr[n + 1];

    float a0=0,a1=0,a2=0,a3=0,a4=0,a5=0,a6=0,a7=0,a8=0,a9=0;
    #pragma unroll 2
    for (int e = lo; e < hi; ++e) {
        float m = bf2f(medge[(size_t)e * 16 + s]);
        const unsigned short* up = u16 + (size_t)e * 48 + g * 12;
        ushort4v ua = *(const ushort4v*)(up);
        ushort4v ub = *(const ushort4v*)(up + 4);
        unsigned int uc = *(const unsigned int*)(up + 8);
        a0 = fmaf(bf2f(ua.x), m, a0); a1 = fmaf(bf2f(ua.y), m, a1);
        a2 = fmaf(bf2f(ua.z), m, a2); a3 = fmaf(bf2f(ua.w), m, a3);
        a4 = fmaf(bf2f(ub.x), m, a4); a5 = fmaf(bf2f(ub.y), m, a5);
        a6 = fmaf(bf2f(ub.z), m, a6); a7 = fmaf(bf2f(ub.w), m, a7);
        a8 = fmaf(bf2f((unsigned short)(uc & 0xFFFFu)), m, a8);
        a9 = fmaf(bf2f((unsigned short)(uc >> 16)), m, a9);
    }
    unsigned short* cp = cat + (size_t)n * KPAD;
    cp[0*64+lane]=f2bf(a0); cp[1*64+lane]=f2bf(a1); cp[2*64+lane]=f2bf(a2);
    cp[3*64+lane]=f2bf(a3); cp[4*64+lane]=f2bf(a4); cp[5*64+lane]=f2bf(a5);
    cp[6*64+lane]=f2bf(a6); cp[7*64+lane]=f2bf(a7); cp[8*64+lane]=f2bf(a8);
    cp[9*64+lane]=f2bf(a9);
    if (lane < SUB)      cp[640 + lane] = f2bf(si[n * SUB + lane]);
    else if (lane < 32)  cp[640 + lane] = 0;   // pad cols 656..671
}

// Fused MFMA MLP: 16 nodes/block, 4 waves; wave w owns output cols [16w,16w+16),
// full K. fc0 uses two independent MFMA accumulator chains for ILP.
__global__ __launch_bounds__(256) void k_mlp(
    const unsigned short* __restrict__ cat,
    const short* __restrict__ w0f, const float* __restrict__ b0,
    const short* __restrict__ w1f, const float* __restrict__ b1,
    const short* __restrict__ w2f, const float* __restrict__ b2,
    float* __restrict__ xi, int l)
{
    __shared__ __align__(16) unsigned short h1[16][72];
    __shared__ __align__(16) unsigned short h2[16][72];
    const int lane = threadIdx.x & 63;
    const int w = threadIdx.x >> 6;
    const int n0 = blockIdx.x * 16;
    const int r = lane & 15, g = lane >> 4;

    // fc0: K=672, 21 MFMA steps split into 2 independent chains
    const short* Ap = (const short*)cat + (size_t)(n0 + r) * KPAD + g * 8;
    const short* Bp = w0f + ((size_t)l * NKK * 256 + w * 64 + lane) * 8;
    float bv = b0[l * HD + w * 16 + r];
    float4v accA = {bv, bv, bv, bv};
    float4v accB = {0.f, 0.f, 0.f, 0.f};
    #pragma unroll 5
    for (int kk = 0; kk < 20; kk += 2) {
        short8 aA = *(const short8*)(Ap + kk * 32);
        short8 bA = *(const short8*)(Bp + (size_t)kk * 2048);
        accA = __builtin_amdgcn_mfma_f32_16x16x32_bf16(aA, bA, accA, 0, 0, 0);
        short8 aB = *(const short8*)(Ap + (kk + 1) * 32);
        short8 bB = *(const short8*)(Bp + (size_t)(kk + 1) * 2048);
        accB = __builtin_amdgcn_mfma_f32_16x16x32_bf16(aB, bB, accB, 0, 0, 0);
    }
    {
        short8 a = *(const short8*)(Ap + 20 * 32);
        short8 b = *(const short8*)(Bp + (size_t)20 * 2048);
        accA = __builtin_amdgcn_mfma_f32_16x16x32_bf16(a, b, accA, 0, 0, 0);
    }
    #pragma unroll
    for (int i = 0; i < 4; ++i)
        h1[g * 4 + i][w * 16 + r] = f2bf(ssp(accA[i] + accB[i]));
    __syncthreads();

    // fc1
    bv = b1[l * HD + w * 16 + r];
    float4v acc1 = {bv, bv, bv, bv};
    #pragma unroll
    for (int kk = 0; kk < 2; ++kk) {
        short8 a = *(const short8*)((const short*)&h1[r][kk * 32 + g * 8]);
        short8 b = *(const short8*)(w1f + ((size_t)(l * 2 + kk) * 256 + w * 64 + lane) * 8);
        acc1 = __builtin_amdgcn_mfma_f32_16x16x32_bf16(a, b, acc1, 0, 0, 0);
    }
    #pragma unroll
    for (int i = 0; i < 4; ++i)
        h2[g * 4 + i][w * 16 + r] = f2bf(ssp(acc1[i]));
    __syncthreads();

    // fc2 + residual
    bv = b2[l * DIM + w * 16 + r];
    float4v acc2 = {bv, bv, bv, bv};
    #pragma unroll
    for (int kk = 0; kk < 2; ++kk) {
        short8 a = *(const short8*)((const short*)&h2[r][kk * 32 + g * 8]);
        short8 b = *(const short8*)(w2f + ((size_t)(l * 2 + kk) * 256 + w * 64 + lane) * 8);
        acc2 = __builtin_amdgcn_mfma_f32_16x16x32_bf16(a, b, acc2, 0, 0, 0);
    }
    #pragma unroll
    for (int i = 0; i < 4; ++i)
        xi[(size_t)(n0 + g * 4 + i) * DIM + w * 16 + r] += acc2[i];
}

extern "C" void kernel_launch(void* const* d_in, const int* in_sizes, int n_in,
                              void* d_out, int out_size, void* d_ws, size_t ws_size,
                              hipStream_t stream) {
    const int*   species = (const int*)  d_in[0];
    const int*   esrc    = (const int*)  d_in[1];
    const int*   edst    = (const int*)  d_in[2];
    const float* dist    = (const float*)d_in[3];
    const float* sw      = (const float*)d_in[4];
    const float* bo      = (const float*)d_in[5];
    const float* Wsp     = (const float*)d_in[6];
    const float* Wsm     = (const float*)d_in[7];
    const float* bsm     = (const float*)d_in[8];
    const float* w0      = (const float*)d_in[9];
    const float* b0      = (const float*)d_in[10];
    const float* w1      = (const float*)d_in[11];
    const float* b1      = (const float*)d_in[12];
    const float* w2      = (const float*)d_in[13];
    const float* b2      = (const float*)d_in[14];

    float* xi = (float*)d_out;   // N x 64 fp32, updated in place

    // ws layout: u16 E*48 ush | si N*16 f | mi16 N*16 ush | medge E*16 ush |
    //            cat N*672 ush | w0f | w1f | w2f | rowptr (all 8B-aligned)
    unsigned short* u16   = (unsigned short*)d_ws;
    float*          si    = (float*)(u16 + (size_t)N_EDGES * 48);
    unsigned short* mi16  = (unsigned short*)(si + (size_t)N_NODES * SUB);
    unsigned short* medge = mi16 + (size_t)N_NODES * SUB;
    unsigned short* cat   = medge + (size_t)N_EDGES * 16;
    short* w0f = (short*)(cat + (size_t)N_NODES * KPAD);
    short* w1f = w0f + (size_t)LAYERS * NKK * 2048;
    short* w2f = w1f + (size_t)LAYERS * 2 * 2048;
    int* rowptr = (int*)(w2f + (size_t)LAYERS * 2 * 2048);

    k_rowptr<<<(N_NODES + 1 + 255) / 256, 256, 0, stream>>>(esrc, rowptr);
    k_u<<<(N_EDGES * 48 + 255) / 256, 256, 0, stream>>>(dist, sw, bo, u16);
    {
        int total = LAYERS * NKK * 2048 + 2 * LAYERS * 2 * 2048;
        k_packw<<<(total + 255) / 256, 256, 0, stream>>>(w0, w1, w2, w0f, w1f, w2f);
    }
    k_init_xi<<<(N_NODES * DIM + 255) / 256, 256, 0, stream>>>(species, Wsp, xi);

    for (int l = 0; l < LAYERS; ++l) {
        k_h<<<(N_NODES * 2 * SUB + 255) / 256, 256, 0, stream>>>(xi, Wsm, bsm, si, mi16, l);
        k_gather<<<(N_EDGES * 4 + 255) / 256, 256, 0, stream>>>(edst, mi16, medge);
        k_agg<<<N_NODES / 4, 256, 0, stream>>>(rowptr, u16, medge, si, cat);
        k_mlp<<<N_NODES / 16, 256, 0, stream>>>(cat, w0f, b0, w1f, b1, w2f, b2, xi, l);
    }
}